// Round 1
// baseline (2003.496 us; speedup 1.0000x reference)
//
#include <hip/hip_runtime.h>

typedef __bf16 bf16x8 __attribute__((ext_vector_type(8)));
typedef __bf16 bf16x4 __attribute__((ext_vector_type(4)));
typedef float f32x4 __attribute__((ext_vector_type(4)));

// ---------------------------------------------------------------------------
// Generic GEMM: C[M,N] = A[M,K] @ W[N,K]^T   (bf16 MFMA compute, fp32 acc)
// TA in {float, __bf16}, W always float, TC in {float, __bf16}.
// Block: 256 threads, 128x128 tile, BK=32. Wave w -> 64x64 quadrant.
// LDS stride 40 bf16 (pad +8): 16B-aligned b128 reads, <=2-way bank alias.
// ---------------------------------------------------------------------------
template <typename TA, typename TC>
__global__ __launch_bounds__(256) void gemm_bt(const TA* __restrict__ A,
                                               const float* __restrict__ W,
                                               TC* __restrict__ C,
                                               int M, int N, int K) {
    __shared__ __bf16 As[128][40];
    __shared__ __bf16 Bs[128][40];
    const int tid  = threadIdx.x;
    const int wave = tid >> 6, lane = tid & 63;
    const int lm = lane & 15, lq = lane >> 4;
    const int wr = wave >> 1, wc = wave & 1;
    const int n0 = blockIdx.x * 128, m0 = blockIdx.y * 128;

    f32x4 acc[4][4];
#pragma unroll
    for (int i = 0; i < 4; ++i)
#pragma unroll
        for (int j = 0; j < 4; ++j) acc[i][j] = (f32x4){0.f, 0.f, 0.f, 0.f};

    for (int k0 = 0; k0 < K; k0 += 32) {
        __syncthreads();  // prev iter's frag reads done before overwrite
        if constexpr (sizeof(TA) == 4) {
            // A tile fp32: 4096 floats, 4 iters x 256 thr x float4
#pragma unroll
            for (int it = 0; it < 4; ++it) {
                int f = it * 1024 + tid * 4;
                int row = f >> 5, kc = f & 31;
                float4 a = *(const float4*)(const void*)(A + (size_t)(m0 + row) * K + k0 + kc);
                bf16x4 v;
                v[0] = (__bf16)a.x; v[1] = (__bf16)a.y; v[2] = (__bf16)a.z; v[3] = (__bf16)a.w;
                *(bf16x4*)&As[row][kc] = v;
            }
        } else {
            // A tile bf16: 4096 elems, 2 iters x 256 thr x 8
#pragma unroll
            for (int it = 0; it < 2; ++it) {
                int f = it * 2048 + tid * 8;
                int row = f >> 5, kc = f & 31;
                *(bf16x8*)&As[row][kc] = *(const bf16x8*)(const void*)(A + (size_t)(m0 + row) * K + k0 + kc);
            }
        }
#pragma unroll
        for (int it = 0; it < 4; ++it) {
            int f = it * 1024 + tid * 4;
            int row = f >> 5, kc = f & 31;
            float4 a = *(const float4*)(const void*)(W + (size_t)(n0 + row) * K + k0 + kc);
            bf16x4 v;
            v[0] = (__bf16)a.x; v[1] = (__bf16)a.y; v[2] = (__bf16)a.z; v[3] = (__bf16)a.w;
            *(bf16x4*)&Bs[row][kc] = v;
        }
        __syncthreads();

        bf16x8 af[4], bfr[4];
#pragma unroll
        for (int i = 0; i < 4; ++i) af[i] = *(const bf16x8*)&As[wr * 64 + i * 16 + lm][lq * 8];
#pragma unroll
        for (int j = 0; j < 4; ++j) bfr[j] = *(const bf16x8*)&Bs[wc * 64 + j * 16 + lm][lq * 8];
#pragma unroll
        for (int i = 0; i < 4; ++i)
#pragma unroll
            for (int j = 0; j < 4; ++j)
                acc[i][j] = __builtin_amdgcn_mfma_f32_16x16x32_bf16(af[i], bfr[j], acc[i][j], 0, 0, 0);
    }

    // Epilogue. C/D layout: col = lane&15, row = (lane>>4)*4 + reg  [m89]
#pragma unroll
    for (int i = 0; i < 4; ++i) {
#pragma unroll
        for (int r = 0; r < 4; ++r) {
            int row = m0 + wr * 64 + i * 16 + lq * 4 + r;
#pragma unroll
            for (int j = 0; j < 4; ++j) {
                int col = n0 + wc * 64 + j * 16 + lm;
                C[(size_t)row * N + col] = (TC)acc[i][j][r];
            }
        }
    }
}

// ---------------------------------------------------------------------------
// In-place RoPE on bf16 [rows, nheads*128]. Thread owns pair (d, d+64):
// race-free in-place. cos[s][d] == cos[s][d+64] (concatenated tables).
// ---------------------------------------------------------------------------
__global__ void rope_kernel(__bf16* __restrict__ X, const float* __restrict__ ct,
                            const float* __restrict__ st, int nheads, int total) {
    int idx = blockIdx.x * 256 + threadIdx.x;
    if (idx >= total) return;
    int d   = idx & 63;
    int hh  = (idx >> 6) % nheads;
    int row = idx / (64 * nheads);   // row = b*2048 + s
    int s   = row & 2047;
    size_t base = (size_t)row * (nheads * 128) + hh * 128 + d;
    float x1 = (float)X[base], x2 = (float)X[base + 64];
    float c = ct[s * 128 + d], sn = st[s * 128 + d];
    X[base]      = (__bf16)(x1 * c - x2 * sn);
    X[base + 64] = (__bf16)(x2 * c + x1 * sn);
}

// ---------------------------------------------------------------------------
// Flash-style causal attention, bf16 MFMA, fp32 online softmax.
// Block = (b, h, 64 q-rows); 4 waves, each owns 16 q-rows.
// KV chunk = 32 positions staged in LDS (K row-major, V transposed).
// ---------------------------------------------------------------------------
__global__ __launch_bounds__(256) void attn_kernel(const __bf16* __restrict__ Q,
                                                   const __bf16* __restrict__ Kg,
                                                   const __bf16* __restrict__ Vg,
                                                   __bf16* __restrict__ O) {
    constexpr int S = 2048;
    __shared__ __bf16 Ks[32][136];   // [kv][hd], pad->stride 272B (2-way alias ok)
    __shared__ __bf16 Vt[128][40];   // [hd][kv] transposed
    __shared__ __bf16 Ps[4][16][40]; // per-wave P scratch (C-layout -> A-layout)

    const int tid  = threadIdx.x;
    const int wave = tid >> 6, lane = tid & 63;
    const int lm = lane & 15, lq = lane >> 4;

    const int qt = blockIdx.x & 31;
    const int h  = (blockIdx.x >> 5) & 31;
    const int b  = blockIdx.x >> 10;
    const int q0 = qt * 64;
    const int kvh = h >> 2;  // GQA: 4 consecutive q-heads share a kv head

    const __bf16* Qb = Q  + (size_t)b * S * 4096 + h * 128;
    const __bf16* Kb = Kg + (size_t)b * S * 1024 + kvh * 128;
    const __bf16* Vb = Vg + (size_t)b * S * 1024 + kvh * 128;

    // Q fragments in registers: A-layout A[m=lane&15][k=quad*8+j]  [m120]
    bf16x8 qf[4];
    const int qrow_a = q0 + wave * 16 + lm;
#pragma unroll
    for (int kk = 0; kk < 4; ++kk)
        qf[kk] = *(const bf16x8*)(const void*)(Qb + (size_t)qrow_a * 4096 + kk * 32 + lq * 8);

    f32x4 o[8];
#pragma unroll
    for (int dt = 0; dt < 8; ++dt) o[dt] = (f32x4){0.f, 0.f, 0.f, 0.f};
    float m_i[4] = {-1e30f, -1e30f, -1e30f, -1e30f};
    float l_i[4] = {0.f, 0.f, 0.f, 0.f};

    const int row_max_wave = q0 + wave * 16 + 15;
    const int nch = (q0 >> 5) + 2;
    const float scale = 0.08838834764831845f;  // 1/sqrt(128)

    for (int ch = 0; ch < nch; ++ch) {
        const int j0 = ch * 32;
        __syncthreads();  // all waves done with previous chunk's LDS
        // stage K chunk [32][128]
#pragma unroll
        for (int p = 0; p < 2; ++p) {
            int f = p * 256 + tid;
            int row = f >> 4, c = f & 15;
            *(bf16x8*)&Ks[row][c * 8] =
                *(const bf16x8*)(const void*)(Kb + (size_t)(j0 + row) * 1024 + c * 8);
        }
        // stage V transposed [128][32]
#pragma unroll
        for (int p = 0; p < 2; ++p) {
            int f = p * 256 + tid;
            int row = f >> 4, c = f & 15;
            bf16x8 v8 = *(const bf16x8*)(const void*)(Vb + (size_t)(j0 + row) * 1024 + c * 8);
#pragma unroll
            for (int e = 0; e < 8; ++e) Vt[c * 8 + e][row] = v8[e];
        }
        __syncthreads();
        if (j0 > row_max_wave) continue;  // fully masked for this wave (barriers above still hit)

        // S tile [16 q x 32 kv] = Q @ K^T
        f32x4 st0 = {0.f, 0.f, 0.f, 0.f}, st1 = {0.f, 0.f, 0.f, 0.f};
#pragma unroll
        for (int kk = 0; kk < 4; ++kk) {
            bf16x8 k0v = *(const bf16x8*)&Ks[lm][kk * 32 + lq * 8];
            bf16x8 k1v = *(const bf16x8*)&Ks[16 + lm][kk * 32 + lq * 8];
            st0 = __builtin_amdgcn_mfma_f32_16x16x32_bf16(qf[kk], k0v, st0, 0, 0, 0);
            st1 = __builtin_amdgcn_mfma_f32_16x16x32_bf16(qf[kk], k1v, st1, 0, 0, 0);
        }

        // online softmax per row r (lane holds rows lq*4+r, cols lm / lm+16)
#pragma unroll
        for (int r = 0; r < 4; ++r) {
            const int row_abs = q0 + wave * 16 + lq * 4 + r;
            float v0 = (j0 + lm      <= row_abs) ? st0[r] * scale : -1e30f;
            float v1 = (j0 + 16 + lm <= row_abs) ? st1[r] * scale : -1e30f;
            float mx = fmaxf(v0, v1);
            mx = fmaxf(mx, __shfl_xor(mx, 1));
            mx = fmaxf(mx, __shfl_xor(mx, 2));
            mx = fmaxf(mx, __shfl_xor(mx, 4));
            mx = fmaxf(mx, __shfl_xor(mx, 8));
            float mn = fmaxf(m_i[r], mx);
            float al = __expf(m_i[r] - mn);
            float p0 = __expf(v0 - mn);  // masked -> exp(-1e30) = 0
            float p1 = __expf(v1 - mn);
            float sm = p0 + p1;
            sm += __shfl_xor(sm, 1);
            sm += __shfl_xor(sm, 2);
            sm += __shfl_xor(sm, 4);
            sm += __shfl_xor(sm, 8);
            l_i[r] = al * l_i[r] + sm;
            m_i[r] = mn;
#pragma unroll
            for (int dt = 0; dt < 8; ++dt) o[dt][r] *= al;
            Ps[wave][lq * 4 + r][lm]      = (__bf16)p0;
            Ps[wave][lq * 4 + r][16 + lm] = (__bf16)p1;
        }
        // wave-private LDS round trip: wait own ds_writes (lgkmcnt(0) only)
        __builtin_amdgcn_s_waitcnt(0xC07F);

        // PV: P [16x32] @ V [32x128]
        bf16x8 pf = *(const bf16x8*)&Ps[wave][lm][lq * 8];
#pragma unroll
        for (int dt = 0; dt < 8; ++dt) {
            bf16x8 vf = *(const bf16x8*)&Vt[dt * 16 + lm][lq * 8];
            o[dt] = __builtin_amdgcn_mfma_f32_16x16x32_bf16(pf, vf, o[dt], 0, 0, 0);
        }
    }

    // epilogue: o / l, write [b, s, h*128 + d]
#pragma unroll
    for (int r = 0; r < 4; ++r) {
        const int row_abs = q0 + wave * 16 + lq * 4 + r;
        float inv = 1.0f / l_i[r];
#pragma unroll
        for (int dt = 0; dt < 8; ++dt)
            O[((size_t)b * S + row_abs) * 4096 + h * 128 + dt * 16 + lm] =
                (__bf16)(o[dt][r] * inv);
    }
}

// ---------------------------------------------------------------------------
extern "C" void kernel_launch(void* const* d_in, const int* in_sizes, int n_in,
                              void* d_out, int out_size, void* d_ws, size_t ws_size,
                              hipStream_t stream) {
    const float* data = (const float*)d_in[0];
    const float* Wq   = (const float*)d_in[1];
    const float* Wk   = (const float*)d_in[2];
    const float* Wv   = (const float*)d_in[3];
    const float* Wo   = (const float*)d_in[4];
    const float* cost = (const float*)d_in[5];
    const float* sint = (const float*)d_in[6];
    float* out = (float*)d_out;

    char* ws = (char*)d_ws;
    __bf16* qb   = (__bf16*)(ws);                       // [4096, 4096] 32 MB
    __bf16* kb   = (__bf16*)(ws + (33554432));          // [4096, 1024]  8 MB
    __bf16* vb   = (__bf16*)(ws + (33554432 + 8388608));// [4096, 1024]  8 MB
    __bf16* attn = (__bf16*)(ws + (33554432 + 2 * 8388608)); // [4096, 4096] 32 MB

    // QKV projections (bf16 out)
    gemm_bt<float, __bf16><<<dim3(32, 32), 256, 0, stream>>>(data, Wq, qb, 4096, 4096, 4096);
    gemm_bt<float, __bf16><<<dim3(8, 32), 256, 0, stream>>>(data, Wk, kb, 4096, 1024, 4096);
    gemm_bt<float, __bf16><<<dim3(8, 32), 256, 0, stream>>>(data, Wv, vb, 4096, 1024, 4096);
    // RoPE in-place on Q and K
    rope_kernel<<<(4096 * 32 * 64) / 256, 256, 0, stream>>>(qb, cost, sint, 32, 4096 * 32 * 64);
    rope_kernel<<<(4096 * 8 * 64) / 256, 256, 0, stream>>>(kb, cost, sint, 8, 4096 * 8 * 64);
    // causal GQA flash attention
    attn_kernel<<<2048, 256, 0, stream>>>(qb, kb, vb, attn);
    // output projection (fp32 out)
    gemm_bt<__bf16, float><<<dim3(32, 32), 256, 0, stream>>>(attn, Wo, out, 4096, 4096, 4096);
}

// Round 2
// 991.579 us; speedup vs baseline: 2.0205x; 2.0205x over previous
//
#include <hip/hip_runtime.h>

typedef __bf16 bf16x8 __attribute__((ext_vector_type(8)));
typedef __bf16 bf16x4 __attribute__((ext_vector_type(4)));
typedef float f32x4 __attribute__((ext_vector_type(4)));

// async global->LDS, 16B per lane. LDS dest must be lane-linear (base + lane*16).
__device__ __forceinline__ void gload_lds16(const __bf16* g, __bf16* l) {
    __builtin_amdgcn_global_load_lds((const __attribute__((address_space(1))) unsigned int*)g,
                                     (__attribute__((address_space(3))) unsigned int*)l,
                                     16, 0, 0);
}

// ---------------------------------------------------------------------------
// Shared epilogue. C/D layout: col = lane&15, row = (lane>>4)*4 + reg  [m89]
// EPI 0: bf16 row-major (stride N)      EPI 1: f32 row-major (stride N)
// EPI 2: V^T (col is d_full, 0..1023)   EPI 3: col<1024 -> kb, else V^T
// V^T layout: vt[((b*8+kvh)*128 + d)*2048 + s], packed bf16x4 along s (4 rows).
// ---------------------------------------------------------------------------
template <int EPI>
__device__ __forceinline__ void store_tile(f32x4 (&acc)[4][4], void* Cp, __bf16* vt,
                                           int N, int m0, int n0, int wr, int wc,
                                           int lm, int lq) {
#pragma unroll
    for (int i = 0; i < 4; ++i) {
        int row0 = m0 + wr * 64 + i * 16 + lq * 4;
#pragma unroll
        for (int j = 0; j < 4; ++j) {
            int gc = n0 + wc * 64 + j * 16 + lm;
            if constexpr (EPI == 1) {
                float* C = (float*)Cp;
#pragma unroll
                for (int r = 0; r < 4; ++r) C[(size_t)(row0 + r) * N + gc] = acc[i][j][r];
            } else if constexpr (EPI == 0) {
                __bf16* C = (__bf16*)Cp;
#pragma unroll
                for (int r = 0; r < 4; ++r) C[(size_t)(row0 + r) * N + gc] = (__bf16)acc[i][j][r];
            } else {
                bool vpath = (EPI == 2) || (gc >= 1024);
                if (!vpath) {
                    __bf16* C = (__bf16*)Cp;
#pragma unroll
                    for (int r = 0; r < 4; ++r) C[(size_t)(row0 + r) * 1024 + gc] = (__bf16)acc[i][j][r];
                } else {
                    int dfull = (EPI == 2) ? gc : gc - 1024;
                    int kvh = dfull >> 7, d = dfull & 127;
                    int bq = row0 >> 11, s = row0 & 2047;
                    bf16x4 v;
#pragma unroll
                    for (int r = 0; r < 4; ++r) v[r] = (__bf16)acc[i][j][r];
                    *(bf16x4*)&vt[(((size_t)bq * 8 + kvh) * 128 + d) * 2048 + s] = v;
                }
            }
        }
    }
}

// ---------------------------------------------------------------------------
// Fast GEMM: C = A[M,K] @ B[N,K]^T, all-bf16, global_load_lds staging (m97),
// XOR-swizzled LDS chunk layout -> 2-way (free) frag reads.
// 128x128 tile, BK=32, 4 waves, 64x64/wave.
// ---------------------------------------------------------------------------
template <int EPI>
__global__ __launch_bounds__(256) void gemm_a16(const __bf16* __restrict__ A,
                                                const __bf16* __restrict__ B,
                                                void* __restrict__ Cp, __bf16* __restrict__ vt,
                                                int M, int N, int K) {
    __shared__ __bf16 As[4096];
    __shared__ __bf16 Bs[4096];
    const int tid = threadIdx.x;
    const int wave = tid >> 6, lane = tid & 63;
    const int lm = lane & 15, lq = lane >> 4;
    const int wr = wave >> 1, wc = wave & 1;
    const int n0 = blockIdx.x * 128, m0 = blockIdx.y * 128;

    f32x4 acc[4][4];
#pragma unroll
    for (int i = 0; i < 4; ++i)
#pragma unroll
        for (int j = 0; j < 4; ++j) acc[i][j] = (f32x4){0.f, 0.f, 0.f, 0.f};

    for (int k0 = 0; k0 < K; k0 += 32) {
        __syncthreads();
        // stage A: 512 16B-chunks; group = 2 rows (8 chunks), swizzle s^=g&7
#pragma unroll
        for (int it = 0; it < 2; ++it) {
            int f = it * 256 + tid;
            int g = f >> 3, s = f & 7, sx = s ^ (g & 7);
            int row = g * 2 + (sx >> 2), kc = (sx & 3) * 8;
            gload_lds16(A + (size_t)(m0 + row) * K + k0 + kc, &As[f * 8]);
        }
#pragma unroll
        for (int it = 0; it < 2; ++it) {
            int f = it * 256 + tid;
            int g = f >> 3, s = f & 7, sx = s ^ (g & 7);
            int row = g * 2 + (sx >> 2), kc = (sx & 3) * 8;
            gload_lds16(B + (size_t)(n0 + row) * K + k0 + kc, &Bs[f * 8]);
        }
        __syncthreads();  // drains vmcnt -> LDS data ready

        bf16x8 af[4], bfr[4];
#pragma unroll
        for (int i = 0; i < 4; ++i) {
            int rf = wr * 64 + i * 16 + lm;
            int g = rf >> 1, w = (rf & 1) * 4 + lq, s = w ^ (g & 7);
            af[i] = *(const bf16x8*)&As[g * 64 + s * 8];
        }
#pragma unroll
        for (int j = 0; j < 4; ++j) {
            int rf = wc * 64 + j * 16 + lm;
            int g = rf >> 1, w = (rf & 1) * 4 + lq, s = w ^ (g & 7);
            bfr[j] = *(const bf16x8*)&Bs[g * 64 + s * 8];
        }
#pragma unroll
        for (int i = 0; i < 4; ++i)
#pragma unroll
            for (int j = 0; j < 4; ++j)
                acc[i][j] = __builtin_amdgcn_mfma_f32_16x16x32_bf16(af[i], bfr[j], acc[i][j], 0, 0, 0);
    }
    store_tile<EPI>(acc, Cp, vt, N, m0, n0, wr, wc, lm, lq);
}

// ---------------------------------------------------------------------------
// Fallback GEMM (round-1 structure): A fp32 or bf16, W fp32, vector-load staging.
// Used only when ws_size is too small for the pre-convert path.
// ---------------------------------------------------------------------------
template <typename TA, int EPI>
__global__ __launch_bounds__(256) void gemm_bt(const TA* __restrict__ A,
                                               const float* __restrict__ W,
                                               void* __restrict__ Cp, __bf16* __restrict__ vt,
                                               int M, int N, int K) {
    __shared__ __bf16 Asl[128][40];
    __shared__ __bf16 Bsl[128][40];
    const int tid = threadIdx.x;
    const int wave = tid >> 6, lane = tid & 63;
    const int lm = lane & 15, lq = lane >> 4;
    const int wr = wave >> 1, wc = wave & 1;
    const int n0 = blockIdx.x * 128, m0 = blockIdx.y * 128;

    f32x4 acc[4][4];
#pragma unroll
    for (int i = 0; i < 4; ++i)
#pragma unroll
        for (int j = 0; j < 4; ++j) acc[i][j] = (f32x4){0.f, 0.f, 0.f, 0.f};

    for (int k0 = 0; k0 < K; k0 += 32) {
        __syncthreads();
        if constexpr (sizeof(TA) == 4) {
#pragma unroll
            for (int it = 0; it < 4; ++it) {
                int f = it * 1024 + tid * 4;
                int row = f >> 5, kc = f & 31;
                float4 a = *(const float4*)(const void*)(A + (size_t)(m0 + row) * K + k0 + kc);
                bf16x4 v;
                v[0] = (__bf16)a.x; v[1] = (__bf16)a.y; v[2] = (__bf16)a.z; v[3] = (__bf16)a.w;
                *(bf16x4*)&Asl[row][kc] = v;
            }
        } else {
#pragma unroll
            for (int it = 0; it < 2; ++it) {
                int f = it * 2048 + tid * 8;
                int row = f >> 5, kc = f & 31;
                *(bf16x8*)&Asl[row][kc] = *(const bf16x8*)(const void*)(A + (size_t)(m0 + row) * K + k0 + kc);
            }
        }
#pragma unroll
        for (int it = 0; it < 4; ++it) {
            int f = it * 1024 + tid * 4;
            int row = f >> 5, kc = f & 31;
            float4 a = *(const float4*)(const void*)(W + (size_t)(n0 + row) * K + k0 + kc);
            bf16x4 v;
            v[0] = (__bf16)a.x; v[1] = (__bf16)a.y; v[2] = (__bf16)a.z; v[3] = (__bf16)a.w;
            *(bf16x4*)&Bsl[row][kc] = v;
        }
        __syncthreads();

        bf16x8 af[4], bfr[4];
#pragma unroll
        for (int i = 0; i < 4; ++i) af[i] = *(const bf16x8*)&Asl[wr * 64 + i * 16 + lm][lq * 8];
#pragma unroll
        for (int j = 0; j < 4; ++j) bfr[j] = *(const bf16x8*)&Bsl[wc * 64 + j * 16 + lm][lq * 8];
#pragma unroll
        for (int i = 0; i < 4; ++i)
#pragma unroll
            for (int j = 0; j < 4; ++j)
                acc[i][j] = __builtin_amdgcn_mfma_f32_16x16x32_bf16(af[i], bfr[j], acc[i][j], 0, 0, 0);
    }
    store_tile<EPI>(acc, Cp, vt, N, m0, n0, wr, wc, lm, lq);
}

// ---------------------------------------------------------------------------
// fp32 -> bf16 conversion, 8 elems/thread
// ---------------------------------------------------------------------------
__global__ void cvt_kernel(const float* __restrict__ in, __bf16* __restrict__ out, int n8) {
    int i = blockIdx.x * 256 + threadIdx.x;
    if (i >= n8) return;
    const float4* p = (const float4*)in + (size_t)i * 2;
    float4 a = p[0], b = p[1];
    bf16x8 v;
    v[0] = (__bf16)a.x; v[1] = (__bf16)a.y; v[2] = (__bf16)a.z; v[3] = (__bf16)a.w;
    v[4] = (__bf16)b.x; v[5] = (__bf16)b.y; v[6] = (__bf16)b.z; v[7] = (__bf16)b.w;
    ((bf16x8*)out)[i] = v;
}

// ---------------------------------------------------------------------------
// In-place RoPE on bf16 [rows, nheads*128]. Thread owns pair (d, d+64).
// ---------------------------------------------------------------------------
__global__ void rope_kernel(__bf16* __restrict__ X, const float* __restrict__ ct,
                            const float* __restrict__ st, int nheads, int total) {
    int idx = blockIdx.x * 256 + threadIdx.x;
    if (idx >= total) return;
    int d   = idx & 63;
    int hh  = (idx >> 6) % nheads;
    int row = idx / (64 * nheads);
    int s   = row & 2047;
    size_t base = (size_t)row * (nheads * 128) + hh * 128 + d;
    float x1 = (float)X[base], x2 = (float)X[base + 64];
    float c = ct[s * 128 + d], sn = st[s * 128 + d];
    X[base]      = (__bf16)(x1 * c - x2 * sn);
    X[base + 64] = (__bf16)(x2 * c + x1 * sn);
}

// ---------------------------------------------------------------------------
// Flash attention v2: block = (b, kvh, 32 q-rows); wave w = q-head kvh*4+w.
// All 4 waves share K/V staging (GQA). KV chunk = 32. V^T pre-transposed in
// global (from V-GEMM epilogue) -> no LDS transpose. Heavy-first qt order.
// ---------------------------------------------------------------------------
__global__ __launch_bounds__(256, 3) void attn2(const __bf16* __restrict__ Q,
                                                const __bf16* __restrict__ Kg,
                                                const __bf16* __restrict__ Vtg,
                                                __bf16* __restrict__ O) {
    __shared__ __bf16 Ks[32 * 136];   // [kv][d], pad 136 -> 2-way frag reads
    __shared__ __bf16 Vt[128 * 40];   // [d][kv], pad 40
    __shared__ __bf16 Ps[4 * 32 * 40];// per-wave P scratch

    const int tid = threadIdx.x;
    const int wave = tid >> 6, lane = tid & 63;
    const int lm = lane & 15, lq = lane >> 4;

    const int qt  = 63 - (blockIdx.x >> 4);          // heavy blocks first (LPT)
    const int bh  = blockIdx.x & 15;
    const int b   = bh >> 3, kvh = bh & 7;
    const int q0  = qt * 32;
    const int h   = kvh * 4 + wave;

    const __bf16* Qb = Q + ((size_t)b * 2048) * 4096 + h * 128;
    const __bf16* Kb = Kg + ((size_t)b * 2048) * 1024 + kvh * 128;
    const __bf16* Vb = Vtg + ((size_t)(b * 8 + kvh) * 128) * 2048;
    __bf16* Pw = &Ps[wave * 32 * 40];

    // Q fragments (A-layout): qf[mf][kk] lane holds Q[q0+mf*16+lm][kk*32+lq*8 ..+7]
    bf16x8 qf[2][4];
#pragma unroll
    for (int mf = 0; mf < 2; ++mf) {
        int row = q0 + mf * 16 + lm;
#pragma unroll
        for (int kk = 0; kk < 4; ++kk)
            qf[mf][kk] = *(const bf16x8*)(const void*)(Qb + (size_t)row * 4096 + kk * 32 + lq * 8);
    }

    f32x4 o[2][8];
#pragma unroll
    for (int mf = 0; mf < 2; ++mf)
#pragma unroll
        for (int dt = 0; dt < 8; ++dt) o[mf][dt] = (f32x4){0.f, 0.f, 0.f, 0.f};
    float m_i[2][4], l_i[2][4];
#pragma unroll
    for (int mf = 0; mf < 2; ++mf)
#pragma unroll
        for (int r = 0; r < 4; ++r) { m_i[mf][r] = -1e30f; l_i[mf][r] = 0.f; }

    const int nch = qt + 1;
    const float scale = 0.08838834764831845f;  // 1/sqrt(128)

    for (int ch = 0; ch < nch; ++ch) {
        const int j0 = ch * 32;
        __syncthreads();
        // stage K [32][128]
#pragma unroll
        for (int it = 0; it < 2; ++it) {
            int f = it * 256 + tid;
            int row = f >> 4, c = (f & 15) * 8;
            *(bf16x8*)&Ks[row * 136 + c] =
                *(const bf16x8*)(const void*)(Kb + (size_t)(j0 + row) * 1024 + c);
        }
        // stage V^T [128][32] straight from global (already transposed)
#pragma unroll
        for (int it = 0; it < 2; ++it) {
            int f = it * 256 + tid;
            int d = f >> 2, kc = (f & 3) * 8;
            *(bf16x8*)&Vt[d * 40 + kc] =
                *(const bf16x8*)(const void*)(Vb + (size_t)d * 2048 + j0 + kc);
        }
        __syncthreads();

        // S = Q K^T : st[mf][nc] = [16q x 16kv]
        f32x4 st[2][2];
        st[0][0] = st[0][1] = st[1][0] = st[1][1] = (f32x4){0.f, 0.f, 0.f, 0.f};
#pragma unroll
        for (int kk = 0; kk < 4; ++kk) {
            bf16x8 k0f = *(const bf16x8*)&Ks[lm * 136 + kk * 32 + lq * 8];
            bf16x8 k1f = *(const bf16x8*)&Ks[(16 + lm) * 136 + kk * 32 + lq * 8];
            st[0][0] = __builtin_amdgcn_mfma_f32_16x16x32_bf16(qf[0][kk], k0f, st[0][0], 0, 0, 0);
            st[0][1] = __builtin_amdgcn_mfma_f32_16x16x32_bf16(qf[0][kk], k1f, st[0][1], 0, 0, 0);
            st[1][0] = __builtin_amdgcn_mfma_f32_16x16x32_bf16(qf[1][kk], k0f, st[1][0], 0, 0, 0);
            st[1][1] = __builtin_amdgcn_mfma_f32_16x16x32_bf16(qf[1][kk], k1f, st[1][1], 0, 0, 0);
        }

        const bool diag = (ch == nch - 1);  // j0 == q0: triangular mask
#pragma unroll
        for (int mf = 0; mf < 2; ++mf) {
#pragma unroll
            for (int r = 0; r < 4; ++r) {
                float v0 = st[mf][0][r] * scale;
                float v1 = st[mf][1][r] * scale;
                if (diag) {
                    int row_loc = mf * 16 + lq * 4 + r;
                    if (lm > row_loc)      v0 = -1e30f;
                    if (16 + lm > row_loc) v1 = -1e30f;
                }
                float mx = fmaxf(v0, v1);
                mx = fmaxf(mx, __shfl_xor(mx, 1));
                mx = fmaxf(mx, __shfl_xor(mx, 2));
                mx = fmaxf(mx, __shfl_xor(mx, 4));
                mx = fmaxf(mx, __shfl_xor(mx, 8));
                float mn = fmaxf(m_i[mf][r], mx);
                float al = __expf(m_i[mf][r] - mn);
                float p0 = __expf(v0 - mn);
                float p1 = __expf(v1 - mn);
                float sm = p0 + p1;
                sm += __shfl_xor(sm, 1);
                sm += __shfl_xor(sm, 2);
                sm += __shfl_xor(sm, 4);
                sm += __shfl_xor(sm, 8);
                l_i[mf][r] = al * l_i[mf][r] + sm;
                m_i[mf][r] = mn;
#pragma unroll
                for (int dt = 0; dt < 8; ++dt) o[mf][dt][r] *= al;
                int ql = mf * 16 + lq * 4 + r;
                Pw[ql * 40 + lm]      = (__bf16)p0;
                Pw[ql * 40 + 16 + lm] = (__bf16)p1;
            }
        }
        __builtin_amdgcn_s_waitcnt(0xC07F);  // lgkmcnt(0): own-wave P writes visible

        // O += P V : A-frags from wave-private Ps, B-frags from shared Vt
        bf16x8 pf0 = *(const bf16x8*)&Pw[lm * 40 + lq * 8];
        bf16x8 pf1 = *(const bf16x8*)&Pw[(16 + lm) * 40 + lq * 8];
#pragma unroll
        for (int dt = 0; dt < 8; ++dt) {
            bf16x8 vf = *(const bf16x8*)&Vt[(dt * 16 + lm) * 40 + lq * 8];
            o[0][dt] = __builtin_amdgcn_mfma_f32_16x16x32_bf16(pf0, vf, o[0][dt], 0, 0, 0);
            o[1][dt] = __builtin_amdgcn_mfma_f32_16x16x32_bf16(pf1, vf, o[1][dt], 0, 0, 0);
        }
    }

    // epilogue
#pragma unroll
    for (int mf = 0; mf < 2; ++mf) {
#pragma unroll
        for (int r = 0; r < 4; ++r) {
            int row = q0 + mf * 16 + lq * 4 + r;
            float inv = 1.0f / l_i[mf][r];
#pragma unroll
            for (int dt = 0; dt < 8; ++dt)
                O[((size_t)b * 2048 + row) * 4096 + h * 128 + dt * 16 + lm] =
                    (__bf16)(o[mf][dt][r] * inv);
        }
    }
}

// ---------------------------------------------------------------------------
extern "C" void kernel_launch(void* const* d_in, const int* in_sizes, int n_in,
                              void* d_out, int out_size, void* d_ws, size_t ws_size,
                              hipStream_t stream) {
    const float* data = (const float*)d_in[0];
    const float* Wq   = (const float*)d_in[1];
    const float* Wk   = (const float*)d_in[2];
    const float* Wv   = (const float*)d_in[3];
    const float* Wo   = (const float*)d_in[4];
    const float* cost = (const float*)d_in[5];
    const float* sint = (const float*)d_in[6];
    float* out = (float*)d_out;

    char* ws = (char*)d_ws;
    // persistent buffers (both paths)
    __bf16* qb   = (__bf16*)(ws);                    // 33.55 MB  [4096,4096]
    __bf16* kb   = (__bf16*)(ws + 33554432);         //  8.39 MB  [4096,1024]
    __bf16* vt   = (__bf16*)(ws + 41943040);         //  8.39 MB  V^T [b,kvh,128,2048]
    __bf16* attn = (__bf16*)(ws + 50331648);         // 33.55 MB  [4096,4096]
    // fast-path extra buffers
    __bf16* dbf  = (__bf16*)(ws + 83886080);         // 33.55 MB  data bf16
    __bf16* wbuf = (__bf16*)(ws + 117440512);        // 33.55 MB  weight bf16 (reused)
    const bool fast = ws_size >= 150994944ULL;

    if (fast) {
        cvt_kernel<<<8192, 256, 0, stream>>>(data, dbf, 2097152);
        cvt_kernel<<<8192, 256, 0, stream>>>(Wq, wbuf, 2097152);
        gemm_a16<0><<<dim3(32, 32), 256, 0, stream>>>(dbf, wbuf, qb, nullptr, 4096, 4096, 4096);
        cvt_kernel<<<2048, 256, 0, stream>>>(Wk, wbuf, 524288);
        cvt_kernel<<<2048, 256, 0, stream>>>(Wv, wbuf + 4194304, 524288);
        gemm_a16<3><<<dim3(16, 32), 256, 0, stream>>>(dbf, wbuf, kb, vt, 4096, 2048, 4096);
    } else {
        gemm_bt<float, 0><<<dim3(32, 32), 256, 0, stream>>>(data, Wq, qb, nullptr, 4096, 4096, 4096);
        gemm_bt<float, 0><<<dim3(8, 32), 256, 0, stream>>>(data, Wk, kb, nullptr, 4096, 1024, 4096);
        gemm_bt<float, 2><<<dim3(8, 32), 256, 0, stream>>>(data, Wv, nullptr, vt, 4096, 1024, 4096);
    }
    rope_kernel<<<(4096 * 32 * 64) / 256, 256, 0, stream>>>(qb, cost, sint, 32, 4096 * 32 * 64);
    rope_kernel<<<(4096 * 8 * 64) / 256, 256, 0, stream>>>(kb, cost, sint, 8, 4096 * 8 * 64);
    attn2<<<1024, 256, 0, stream>>>(qb, kb, vt, attn);
    if (fast) {
        cvt_kernel<<<8192, 256, 0, stream>>>(Wo, wbuf, 2097152);
        gemm_a16<1><<<dim3(32, 32), 256, 0, stream>>>(attn, wbuf, out, nullptr, 4096, 4096, 4096);
    } else {
        gemm_bt<__bf16, 1><<<dim3(32, 32), 256, 0, stream>>>(attn, Wo, out, nullptr, 4096, 4096, 4096);
    }
}